// Round 2
// baseline (2181.407 us; speedup 1.0000x reference)
//
#include <hip/hip_runtime.h>
#include <hip/hip_bf16.h>
#include <stdint.h>

// Problem constants (B=8, S=2048, D=1024, E=8, H=4096)
#define NTOK 16384          // B*S
#define DDIM 1024
#define NEXP 8
#define HDIM 4096
#define CAP  5120           // 2 * int(1.25 * ceil(N/E))
#define ECAP 40960          // NEXP*CAP

typedef __bf16 bf16x8 __attribute__((ext_vector_type(8)));
typedef float  f32x4  __attribute__((ext_vector_type(4)));

typedef const __attribute__((address_space(1))) void* gas_cvp;
typedef __attribute__((address_space(3))) void* las_vp;

__device__ __forceinline__ void gload_lds16(const void* g, void* l) {
  __builtin_amdgcn_global_load_lds((gas_cvp)g, (las_vp)l, 16, 0, 0);
}

// ---------------- weight conversion (fc1: [E][H][D] f32 -> bf16) ----------
__global__ __launch_bounds__(256) void convert_f32_bf16(
    const float* __restrict__ in, __hip_bfloat16* __restrict__ out, int n4) {
  int i = blockIdx.x * 256 + threadIdx.x;
  int stride = gridDim.x * 256;
  for (; i < n4; i += stride) {
    float4 v = ((const float4*)in)[i];
    union { __hip_bfloat16 h[4]; uint2 u; } cv;
    cv.h[0] = __float2bfloat16(v.x); cv.h[1] = __float2bfloat16(v.y);
    cv.h[2] = __float2bfloat16(v.z); cv.h[3] = __float2bfloat16(v.w);
    ((uint2*)out)[i] = cv.u;
  }
}

// fc2_w [E][H][D] f32 -> [E][D][H] bf16
__global__ __launch_bounds__(256) void transpose_fc2(
    const float* __restrict__ in, __hip_bfloat16* __restrict__ out) {
  __shared__ float tile[64][65];
  const int e = blockIdx.z;
  const int h0 = blockIdx.x * 64, d0 = blockIdx.y * 64;
  const int c = threadIdx.x & 63, r = threadIdx.x >> 6;  // r in 0..3
  const float* src = in + ((size_t)e * HDIM + h0) * DDIM + d0;
#pragma unroll
  for (int j = 0; j < 16; ++j)
    tile[r + j * 4][c] = src[(size_t)(r + j * 4) * DDIM + c];
  __syncthreads();
  __hip_bfloat16* dst = out + ((size_t)e * DDIM + d0) * HDIM + h0;
#pragma unroll
  for (int j = 0; j < 16; ++j)
    dst[(size_t)(r + j * 4) * HDIM + c] = __float2bfloat16(tile[c][r + j * 4]);
}

// ---------------- gating: scores, top-2, normalized gates ----------------
__global__ __launch_bounds__(256) void gating_kernel(
    const float* __restrict__ x, const float* __restrict__ wg,
    int* __restrict__ idx, float* __restrict__ gates) {
  __shared__ float wgT[NEXP][DDIM];  // 32 KB
  const int t = threadIdx.x;
  for (int i = t; i < NEXP * DDIM; i += 256) {
    int d = i >> 3, e = i & 7;
    wgT[e][d] = wg[i];  // wg is [D][E] row-major
  }
  __syncthreads();
  const int wid = t >> 6, lane = t & 63;
  const int n = blockIdx.x * 4 + wid;
  const float* xr = x + (size_t)n * DDIM;
  double acc[NEXP] = {0, 0, 0, 0, 0, 0, 0, 0};
  for (int i = 0; i < DDIM / 64; ++i) {
    int d = i * 64 + lane;
    double xv = (double)xr[d];
#pragma unroll
    for (int e = 0; e < NEXP; ++e) acc[e] += xv * (double)wgT[e][d];
  }
#pragma unroll
  for (int e = 0; e < NEXP; ++e) {
#pragma unroll
    for (int o = 32; o > 0; o >>= 1) acc[e] += __shfl_xor(acc[e], o, 64);
  }
  if (lane == 0) {
    int e1 = 0; double s1 = acc[0];
    for (int e = 1; e < NEXP; ++e) if (acc[e] > s1) { s1 = acc[e]; e1 = e; }
    int e2 = -1; double s2 = -1e300;
    for (int e = 0; e < NEXP; ++e)
      if (e != e1 && acc[e] > s2) { s2 = acc[e]; e2 = e; }
    // softmax then renormalize over top-2 == 2-way softmax of raw scores
    double g1 = 1.0 / (1.0 + exp(s2 - s1));
    idx[n * 2 + 0] = e1;
    idx[n * 2 + 1] = e2;
    gates[n * 2 + 0] = (float)g1;
    gates[n * 2 + 1] = (float)(1.0 - g1);
  }
}

// ---------------- rank scan (tutel k-slot-major positions) ----------------
__global__ __launch_bounds__(1024) void scan_kernel(
    const int* __restrict__ idx, int* __restrict__ pos, float* __restrict__ gates) {
  const int t = threadIdx.x;
  const int w = t >> 6, lane = t & 63;
  const int k = w >> 3, e = w & 7;  // wave owns column (k, e)
  int base = 0;
  if (k == 1) {  // offset[1][e] = counts[0][e]
    int cnt = 0;
    for (int i = 0; i < NTOK / 64; ++i) {
      unsigned long long m = __ballot(idx[(i * 64 + lane) * 2 + 0] == e);
      cnt += __popcll(m);
    }
    base = cnt;
  }
  const unsigned long long ltmask = (1ull << lane) - 1ull;
  for (int i = 0; i < NTOK / 64; ++i) {
    const int n = i * 64 + lane;
    const int my = idx[n * 2 + k];
    unsigned long long m = __ballot(my == e);
    if (my == e) {
      int rank = base + __popcll(m & ltmask);
      bool kept = rank < CAP;
      pos[n * 2 + k] = kept ? e * CAP + rank : ECAP;
      if (!kept) gates[n * 2 + k] = 0.f;
    }
    base += __popcll(m);
  }
}

// ---------------- dispatch scatter (f32 -> bf16 rows) ----------------
__global__ __launch_bounds__(256) void dispatch_kernel(
    const float* __restrict__ x, const int* __restrict__ pos,
    __hip_bfloat16* __restrict__ disp) {
  const int b = blockIdx.x;
  const int n = b >> 1, k = b & 1;
  const int p = pos[n * 2 + k];
  if (p >= ECAP) return;
  const float4 v = ((const float4*)(x + (size_t)n * DDIM))[threadIdx.x];
  union { __hip_bfloat16 h[4]; uint2 u; } cv;
  cv.h[0] = __float2bfloat16(v.x); cv.h[1] = __float2bfloat16(v.y);
  cv.h[2] = __float2bfloat16(v.z); cv.h[3] = __float2bfloat16(v.w);
  ((uint2*)(disp + (size_t)p * DDIM))[threadIdx.x] = cv.u;
}

// ---------------- GEMM: A[M,K] x Bt[N,K] -> C[M,N], single expert ----------
// EPI 0: C = bf16 silu(acc + bias[col]);  EPI 1: C = bf16 (acc + bias[col])
template <int EPI>
__global__ __launch_bounds__(256) void gemm_bt(
    const __hip_bfloat16* __restrict__ A, const __hip_bfloat16* __restrict__ B,
    const float* __restrict__ bias, __hip_bfloat16* __restrict__ C,
    int K, int N) {
  __shared__ __attribute__((aligned(16))) __hip_bfloat16 As[128 * 32];
  __shared__ __attribute__((aligned(16))) __hip_bfloat16 Bs[128 * 32];
  const int t = threadIdx.x;
  const int lane = t & 63;
  const int m0 = blockIdx.x * 128, n0 = blockIdx.y * 128;
  const __hip_bfloat16* Ae = A + (size_t)m0 * K;
  const __hip_bfloat16* Be = B + (size_t)n0 * K;
  const int wv = t >> 6;
  const int wm = (wv >> 1) * 64, wn = (wv & 1) * 64;
  const int fr = lane & 15;
  const int fk = (lane >> 4) * 8;
  f32x4 acc[4][4];
#pragma unroll
  for (int m = 0; m < 4; ++m)
#pragma unroll
    for (int n = 0; n < 4; ++n) acc[m][n] = (f32x4){0.f, 0.f, 0.f, 0.f};

  for (int kt = 0; kt < K; kt += 32) {
#pragma unroll
    for (int p = 0; p < 2; ++p) {
      const int c = p * 256 + t;           // 16B chunk id, 0..511
      const int row = c >> 2;              // 4 chunks per 32-col row
      const int col = (c & 3) * 8;         // bf16 col
      gload_lds16(Ae + (size_t)row * K + kt + col, (char*)As + (size_t)c * 16);
      gload_lds16(Be + (size_t)row * K + kt + col, (char*)Bs + (size_t)c * 16);
    }
    __syncthreads();  // compiler inserts vmcnt(0) drain
    bf16x8 aF[4], bF[4];
#pragma unroll
    for (int m = 0; m < 4; ++m)
      aF[m] = *reinterpret_cast<const bf16x8*>(As + (size_t)(wm + m * 16 + fr) * 32 + fk);
#pragma unroll
    for (int n = 0; n < 4; ++n)
      bF[n] = *reinterpret_cast<const bf16x8*>(Bs + (size_t)(wn + n * 16 + fr) * 32 + fk);
#pragma unroll
    for (int m = 0; m < 4; ++m)
#pragma unroll
      for (int n = 0; n < 4; ++n)
        acc[m][n] = __builtin_amdgcn_mfma_f32_16x16x32_bf16(aF[m], bF[n], acc[m][n], 0, 0, 0);
    __syncthreads();
  }

  // epilogue: C/D layout col=lane&15, row=(lane>>4)*4+j  [m89-verified]
#pragma unroll
  for (int m = 0; m < 4; ++m) {
    const int row = m0 + wm + m * 16 + (lane >> 4) * 4;
#pragma unroll
    for (int n = 0; n < 4; ++n) {
      const int col = n0 + wn + n * 16 + fr;
      const float bc = bias[col];
#pragma unroll
      for (int j = 0; j < 4; ++j) {
        float v = acc[m][n][j] + bc;
        if (EPI == 0) v = v / (1.f + __expf(-v));  // silu
        C[(size_t)(row + j) * N + col] = __float2bfloat16(v);
      }
    }
  }
}

// ---------------- combine + residual + LayerNorm ----------------
__device__ __forceinline__ float blk_sum256(float v, volatile float* red) {
#pragma unroll
  for (int o = 32; o > 0; o >>= 1) v += __shfl_xor(v, o, 64);
  const int w = threadIdx.x >> 6;
  if ((threadIdx.x & 63) == 0) red[w] = v;
  __syncthreads();
  v = red[0] + red[1] + red[2] + red[3];
  __syncthreads();
  return v;
}

__global__ __launch_bounds__(256) void combine_ln(
    const float* __restrict__ x, const __hip_bfloat16* __restrict__ y,
    const int* __restrict__ pos, const float* __restrict__ gates,
    const float* __restrict__ gamma, const float* __restrict__ beta,
    float* __restrict__ out) {
  __shared__ float red[4];
  const int n = blockIdx.x;
  const int t = threadIdx.x;
  float4 v = ((const float4*)(x + (size_t)n * DDIM))[t];
  const int p0 = pos[n * 2 + 0], p1 = pos[n * 2 + 1];
  const float g0 = gates[n * 2 + 0], g1 = gates[n * 2 + 1];
  if (p0 < ECAP) {
    union { uint2 u; __hip_bfloat16 h[4]; } a;
    a.u = ((const uint2*)(y + (size_t)p0 * DDIM))[t];
    v.x += g0 * __bfloat162float(a.h[0]); v.y += g0 * __bfloat162float(a.h[1]);
    v.z += g0 * __bfloat162float(a.h[2]); v.w += g0 * __bfloat162float(a.h[3]);
  }
  if (p1 < ECAP) {
    union { uint2 u; __hip_bfloat16 h[4]; } a;
    a.u = ((const uint2*)(y + (size_t)p1 * DDIM))[t];
    v.x += g1 * __bfloat162float(a.h[0]); v.y += g1 * __bfloat162float(a.h[1]);
    v.z += g1 * __bfloat162float(a.h[2]); v.w += g1 * __bfloat162float(a.h[3]);
  }
  float s = blk_sum256(v.x + v.y + v.z + v.w, red);
  const float mean = s * (1.f / DDIM);
  float dx = v.x - mean, dy = v.y - mean, dz = v.z - mean, dw = v.w - mean;
  float sq = blk_sum256(dx * dx + dy * dy + dz * dz + dw * dw, red);
  const float rstd = rsqrtf(sq * (1.f / DDIM) + 1e-5f);
  const float4 ga = ((const float4*)gamma)[t];
  const float4 be = ((const float4*)beta)[t];
  float4 o;
  o.x = dx * rstd * ga.x + be.x;
  o.y = dy * rstd * ga.y + be.y;
  o.z = dz * rstd * ga.z + be.z;
  o.w = dw * rstd * ga.w + be.w;
  ((float4*)(out + (size_t)n * DDIM))[t] = o;
}

// ---------------- launch ----------------
extern "C" void kernel_launch(void* const* d_in, const int* in_sizes, int n_in,
                              void* d_out, int out_size, void* d_ws, size_t ws_size,
                              hipStream_t stream) {
  (void)in_sizes; (void)n_in; (void)out_size;
  const float* x     = (const float*)d_in[0];
  const float* wg    = (const float*)d_in[1];
  const float* fc1w  = (const float*)d_in[2];
  const float* fc1b  = (const float*)d_in[3];
  const float* fc2w  = (const float*)d_in[4];
  const float* fc2b  = (const float*)d_in[5];
  const float* gamma = (const float*)d_in[6];
  const float* beta  = (const float*)d_in[7];
  float* out = (float*)d_out;

  // Workspace layout (total 260,440,064 B < 256 MiB):
  //   idx    [0,        128K)
  //   gates  [128K,     256K)
  //   pos    [256K,     384K)
  //   fc1wb  [384K,     +64M)   bf16 [E][H][D]
  //   fc2tb  (+64M,     +64M)   bf16 [E][D][H]
  //   dispy  (+64M,     +80M)   bf16 [E][C][D] — disp before gemm2(e), y after
  //   hbuf   (+80M,     +40M)   bf16 [C][H]    — single expert, reused
  char* ws = (char*)d_ws;
  int*            idx   = (int*)(ws + 0);
  float*          gates = (float*)(ws + 131072);
  int*            pos   = (int*)(ws + 262144);
  __hip_bfloat16* fc1wb = (__hip_bfloat16*)(ws + 393216);
  __hip_bfloat16* fc2tb = (__hip_bfloat16*)(ws + 67502080);
  __hip_bfloat16* dispy = (__hip_bfloat16*)(ws + 134610944);
  __hip_bfloat16* hbuf  = (__hip_bfloat16*)(ws + 218497024);
  if (ws_size < 260440064ull) return;  // diagnostic: zero output, no fault

  convert_f32_bf16<<<4096, 256, 0, stream>>>(fc1w, fc1wb, NEXP * HDIM * DDIM / 4);
  transpose_fc2<<<dim3(HDIM / 64, DDIM / 64, NEXP), 256, 0, stream>>>(fc2w, fc2tb);
  gating_kernel<<<NTOK / 4, 256, 0, stream>>>(x, wg, idx, gates);
  scan_kernel<<<1, 1024, 0, stream>>>(idx, pos, gates);
  dispatch_kernel<<<NTOK * 2, 256, 0, stream>>>(x, pos, dispy);
  for (int e = 0; e < NEXP; ++e) {
    __hip_bfloat16* de = dispy + (size_t)e * CAP * DDIM;
    gemm_bt<0><<<dim3(CAP / 128, HDIM / 128), 256, 0, stream>>>(
        de, fc1wb + (size_t)e * HDIM * DDIM, fc1b + (size_t)e * HDIM,
        hbuf, DDIM, HDIM);
    gemm_bt<1><<<dim3(CAP / 128, DDIM / 128), 256, 0, stream>>>(
        hbuf, fc2tb + (size_t)e * DDIM * HDIM, fc2b + (size_t)e * DDIM,
        de, HDIM, DDIM);
  }
  combine_ln<<<NTOK, 256, 0, stream>>>(x, dispy, pos, gates, gamma, beta, out);
}